// Round 12
// baseline (145.082 us; speedup 1.0000x reference)
//
#include <hip/hip_runtime.h>

#define N_NODES 100000
#define D 128

typedef unsigned short ushort_t;
typedef unsigned char uchar_t;
typedef __attribute__((ext_vector_type(8))) short short8;
typedef __attribute__((ext_vector_type(4))) float f32x4;

// round-to-nearest-even f32 -> bf16 bits (finite inputs)
__device__ __forceinline__ unsigned f2bf(float x) {
    unsigned u = __float_as_uint(x);
    return (u + 0x7fffu + ((u >> 16) & 1u)) >> 16;
}

// ---------------------------------------------------------------------------
// Kernel 1: W -> MFMA A-fragment-ordered bf16 (Wfrag).
// ---------------------------------------------------------------------------
__global__ __launch_bounds__(64)
void build_wfrag_kernel(const float* __restrict__ W,
                        ushort_t* __restrict__ Wfrag) {
    const int t  = blockIdx.x;      // 0..31 = jt*4 + kt
    const int jt = t >> 2, kt = t & 3;
    const int l  = threadIdx.x;
    const float* src = W + (size_t)(jt * 16 + (l & 15)) * D + kt * 32 + (l >> 4) * 8;
    const float4 p0 = *reinterpret_cast<const float4*>(src);
    const float4 p1 = *reinterpret_cast<const float4*>(src + 4);
    uint4 o;
    o.x = f2bf(p0.x) | (f2bf(p0.y) << 16);
    o.y = f2bf(p0.z) | (f2bf(p0.w) << 16);
    o.z = f2bf(p1.x) | (f2bf(p1.y) << 16);
    o.w = f2bf(p1.z) | (f2bf(p1.w) << 16);
    *reinterpret_cast<uint4*>(Wfrag + ((size_t)t * 64 + l) * 8) = o;
}

// ---------------------------------------------------------------------------
// Kernel 2: G = H @ W^T via MFMA, quantized per-node to uint8 (+128 bias):
//   Gq[node][j] = round(g/s) + 128, s = scales[node] = rowmax|g|/127.
// Row = 128 B = ONE cache line per edge in the gather.
// ---------------------------------------------------------------------------
__global__ __launch_bounds__(256)
void gemm_Gq_kernel(const float* __restrict__ h,
                    const ushort_t* __restrict__ Wfrag,
                    uchar_t* __restrict__ Gq,
                    float* __restrict__ scales) {
    const int wave = threadIdx.x >> 6;
    const int l    = threadIdx.x & 63;
    const int tile = blockIdx.x * 4 + wave;
    if (tile >= N_NODES / 16) return;
    const int n0   = tile * 16;
    const int lrow = l & 15;
    const int lk   = l >> 4;

    union { short8 v; ushort_t u[8]; } bfrag[4];
    const float* hp = h + (size_t)(n0 + lrow) * D + lk * 8;
#pragma unroll
    for (int kt = 0; kt < 4; ++kt) {
        const float4 q0 = *reinterpret_cast<const float4*>(hp + kt * 32);
        const float4 q1 = *reinterpret_cast<const float4*>(hp + kt * 32 + 4);
        bfrag[kt].u[0] = (ushort_t)f2bf(q0.x);
        bfrag[kt].u[1] = (ushort_t)f2bf(q0.y);
        bfrag[kt].u[2] = (ushort_t)f2bf(q0.z);
        bfrag[kt].u[3] = (ushort_t)f2bf(q0.w);
        bfrag[kt].u[4] = (ushort_t)f2bf(q1.x);
        bfrag[kt].u[5] = (ushort_t)f2bf(q1.y);
        bfrag[kt].u[6] = (ushort_t)f2bf(q1.z);
        bfrag[kt].u[7] = (ushort_t)f2bf(q1.w);
    }

    const uint4* wf = reinterpret_cast<const uint4*>(Wfrag) + l;
    f32x4 acc[8];
#pragma unroll
    for (int jt = 0; jt < 8; ++jt) {
        acc[jt] = (f32x4){0.f, 0.f, 0.f, 0.f};
#pragma unroll
        for (int kt = 0; kt < 4; ++kt) {
            union { uint4 q; short8 v; } af;
            af.q = wf[(jt * 4 + kt) * 64];
            acc[jt] = __builtin_amdgcn_mfma_f32_16x16x32_bf16(
                af.v, bfrag[kt].v, acc[jt], 0, 0, 0);
        }
    }

    float amax = 0.f;
#pragma unroll
    for (int jt = 0; jt < 8; ++jt) {
#pragma unroll
        for (int r = 0; r < 4; ++r) amax = fmaxf(amax, fabsf(acc[jt][r]));
    }
    amax = fmaxf(amax, __shfl_xor(amax, 16));
    amax = fmaxf(amax, __shfl_xor(amax, 32));
    const float s   = amax > 0.f ? amax * (1.f / 127.f) : 1.f;
    const float inv = amax > 0.f ? 127.f / amax : 0.f;

#pragma unroll
    for (int jt = 0; jt < 8; ++jt) {
        const unsigned q0 = (unsigned)((int)rintf(acc[jt][0] * inv) + 128);
        const unsigned q1 = (unsigned)((int)rintf(acc[jt][1] * inv) + 128);
        const unsigned q2 = (unsigned)((int)rintf(acc[jt][2] * inv) + 128);
        const unsigned q3 = (unsigned)((int)rintf(acc[jt][3] * inv) + 128);
        const unsigned pk = q0 | (q1 << 8) | (q2 << 16) | (q3 << 24);
        *reinterpret_cast<unsigned*>(
            Gq + (size_t)(n0 + lrow) * D + jt * 16 + lk * 4) = pk;
    }
    if (l < 16) scales[n0 + l] = s;
}

// ---------------------------------------------------------------------------
// Kernel 3 (prep sweep): per edge e, (a) boundary-detect row_ptr from the
// SORTED edge_rows, (b) vals2[e] = vals[e] * scales[cols[e]] (fold the
// dequant scale off the gather's critical path). Runs after gemm_Gq.
// ---------------------------------------------------------------------------
__global__ __launch_bounds__(256)
void prep_kernel(const int* __restrict__ rows,
                 const int* __restrict__ cols,
                 const float* __restrict__ vals,
                 const float* __restrict__ scales,
                 int* __restrict__ row_ptr,
                 float* __restrict__ vals2, int n_edges) {
    const int e = blockIdx.x * 256 + threadIdx.x;
    if (e >= n_edges) return;

    vals2[e] = vals[e] * scales[cols[e]];

    const int r0 = rows[e];
    if (e == 0) {
        for (int r = 0; r <= r0; ++r) row_ptr[r] = 0;
    }
    if (e + 1 < n_edges) {
        const int r1 = rows[e + 1];
        for (int r = r0 + 1; r <= r1; ++r) row_ptr[r] = e + 1;
    } else {
        for (int r = r0 + 1; r <= N_NODES; ++r) row_ptr[r] = n_edges;
    }
}

// ---------------------------------------------------------------------------
// Kernel 4: out = relu(S @ dequant(Gq) + b). One node per 16-lane group
// (R6 structure, best measured). Lane il owns feats il*8..il*8+7 (8 int8 =
// uint2 load; group row = 128B = ONE cache line per edge). Depth-8 unroll.
// vals2 pre-folded -> no scales gather in the hot loop. 32-bit Gq addressing.
// Non-temporal on the single-touch streams (cols, vals2, out) so they don't
// evict Gq from L2.
// ---------------------------------------------------------------------------
__device__ __forceinline__ void accq(float* a, float& vsum, float vs, uint2 g) {
    a[0] += vs * (float)(g.x & 0xffu);
    a[1] += vs * (float)((g.x >> 8) & 0xffu);
    a[2] += vs * (float)((g.x >> 16) & 0xffu);
    a[3] += vs * (float)(g.x >> 24);
    a[4] += vs * (float)(g.y & 0xffu);
    a[5] += vs * (float)((g.y >> 8) & 0xffu);
    a[6] += vs * (float)((g.y >> 16) & 0xffu);
    a[7] += vs * (float)(g.y >> 24);
    vsum += vs;
}

__global__ __launch_bounds__(256)
void gconv_gather_q_kernel(const int* __restrict__ cols,
                           const float* __restrict__ vals2,
                           const uchar_t* __restrict__ Gq,
                           const float* __restrict__ bias,
                           const int* __restrict__ row_ptr,
                           float* __restrict__ out) {
    const int tid  = blockIdx.x * 256 + threadIdx.x;
    const int node = tid >> 4;
    const int il   = tid & 15;
    const unsigned il8 = (unsigned)il * 8u;

    int e = row_ptr[node];
    const int end = row_ptr[node + 1];

    float a[8];
#pragma unroll
    for (int j = 0; j < 8; ++j) a[j] = 0.f;
    float vsum = 0.f;

    for (; e + 7 < end; e += 8) {
        int   c[8];
        float v[8];
        uint2 g[8];
#pragma unroll
        for (int i = 0; i < 8; ++i) c[i] = __builtin_nontemporal_load(cols + e + i);
#pragma unroll
        for (int i = 0; i < 8; ++i) v[i] = __builtin_nontemporal_load(vals2 + e + i);
#pragma unroll
        for (int i = 0; i < 8; ++i)
            g[i] = *reinterpret_cast<const uint2*>(Gq + (((unsigned)c[i] << 7) + il8));
#pragma unroll
        for (int i = 0; i < 8; ++i) accq(a, vsum, v[i], g[i]);
    }
    for (; e < end; ++e) {
        const int   c = __builtin_nontemporal_load(cols + e);
        const float v = __builtin_nontemporal_load(vals2 + e);
        const uint2 g = *reinterpret_cast<const uint2*>(Gq + (((unsigned)c << 7) + il8));
        accq(a, vsum, v, g);
    }

    const float4 b0 = *reinterpret_cast<const float4*>(bias + il8);
    const float4 b1 = *reinterpret_cast<const float4*>(bias + il8 + 4);
    const float corr = 128.f * vsum;
    f32x4 r0, r1;
    r0[0] = a[0] - corr + b0.x; r0[1] = a[1] - corr + b0.y;
    r0[2] = a[2] - corr + b0.z; r0[3] = a[3] - corr + b0.w;
    r1[0] = a[4] - corr + b1.x; r1[1] = a[5] - corr + b1.y;
    r1[2] = a[6] - corr + b1.z; r1[3] = a[7] - corr + b1.w;
#pragma unroll
    for (int i = 0; i < 4; ++i) {
        r0[i] = r0[i] > 0.f ? r0[i] : 0.f;
        r1[i] = r1[i] > 0.f ? r1[i] : 0.f;
    }
    float* op = out + (size_t)node * D + il8;
    __builtin_nontemporal_store(r0, reinterpret_cast<f32x4*>(op));
    __builtin_nontemporal_store(r1, reinterpret_cast<f32x4*>(op + 4));
}

// ---------------------------------------------------------------------------
extern "C" void kernel_launch(void* const* d_in, const int* in_sizes, int n_in,
                              void* d_out, int out_size, void* d_ws,
                              size_t ws_size, hipStream_t stream) {
    const int*   edge_rows = (const int*)d_in[0];
    const int*   edge_cols = (const int*)d_in[1];
    const float* edge_vals = (const float*)d_in[2];
    const float* h         = (const float*)d_in[3];
    const float* W         = (const float*)d_in[4];
    const float* b         = (const float*)d_in[5];
    float*       out       = (float*)d_out;

    const int n_edges = in_sizes[0];

    // ws: [Wfrag 32K|pad64K][row_ptr 400K|pad512K][scales 400K|pad512K]
    //     [Gq 12.8M][vals2 12.8M]   total ~26.8MB
    const size_t OFF_RP = 64 * 1024;
    const size_t OFF_SC = OFF_RP + 512 * 1024;
    const size_t OFF_GQ = OFF_SC + 512 * 1024;
    const size_t OFF_V2 = OFF_GQ + (size_t)N_NODES * D;

    ushort_t* Wfrag   = (ushort_t*)d_ws;
    int*      row_ptr = (int*)((char*)d_ws + OFF_RP);
    float*    scales  = (float*)((char*)d_ws + OFF_SC);
    uchar_t*  Gq      = (uchar_t*)((char*)d_ws + OFF_GQ);
    float*    vals2   = (float*)((char*)d_ws + OFF_V2);

    build_wfrag_kernel<<<32, 64, 0, stream>>>(W, Wfrag);

    const int n_tiles     = N_NODES / 16;  // 6250
    const int gemm_blocks = (n_tiles + 3) / 4;
    gemm_Gq_kernel<<<gemm_blocks, 256, 0, stream>>>(h, Wfrag, Gq, scales);

    prep_kernel<<<(n_edges + 255) / 256, 256, 0, stream>>>(
        edge_rows, edge_cols, edge_vals, scales, row_ptr, vals2, n_edges);

    const int gather_blocks = N_NODES * 16 / 256;  // 6250
    gconv_gather_q_kernel<<<gather_blocks, 256, 0, stream>>>(
        edge_cols, vals2, Gq, b, row_ptr, out);
}

// Round 13
// 127.930 us; speedup vs baseline: 1.1341x; 1.1341x over previous
//
#include <hip/hip_runtime.h>

#define N_NODES 100000
#define D 128

typedef unsigned short ushort_t;
typedef unsigned char uchar_t;
typedef __attribute__((ext_vector_type(8))) short short8;
typedef __attribute__((ext_vector_type(4))) float f32x4;

// round-to-nearest-even f32 -> bf16 bits (finite inputs)
__device__ __forceinline__ unsigned f2bf(float x) {
    unsigned u = __float_as_uint(x);
    return (u + 0x7fffu + ((u >> 16) & 1u)) >> 16;
}

// ---------------------------------------------------------------------------
// Kernel 1: W -> MFMA A-fragment-ordered bf16 (Wfrag).
// ---------------------------------------------------------------------------
__global__ __launch_bounds__(64)
void build_wfrag_kernel(const float* __restrict__ W,
                        ushort_t* __restrict__ Wfrag) {
    const int t  = blockIdx.x;      // 0..31 = jt*4 + kt
    const int jt = t >> 2, kt = t & 3;
    const int l  = threadIdx.x;
    const float* src = W + (size_t)(jt * 16 + (l & 15)) * D + kt * 32 + (l >> 4) * 8;
    const float4 p0 = *reinterpret_cast<const float4*>(src);
    const float4 p1 = *reinterpret_cast<const float4*>(src + 4);
    uint4 o;
    o.x = f2bf(p0.x) | (f2bf(p0.y) << 16);
    o.y = f2bf(p0.z) | (f2bf(p0.w) << 16);
    o.z = f2bf(p1.x) | (f2bf(p1.y) << 16);
    o.w = f2bf(p1.z) | (f2bf(p1.w) << 16);
    *reinterpret_cast<uint4*>(Wfrag + ((size_t)t * 64 + l) * 8) = o;
}

// ---------------------------------------------------------------------------
// Kernel 2: G = H @ W^T via MFMA, quantized per-node to uint8 (+128 bias):
//   Gq[node][j] = round(g/s) + 128, s = scales[node] = rowmax|g|/127.
// Row = 128 B = ONE cache line per edge in the gather.
// ---------------------------------------------------------------------------
__global__ __launch_bounds__(256)
void gemm_Gq_kernel(const float* __restrict__ h,
                    const ushort_t* __restrict__ Wfrag,
                    uchar_t* __restrict__ Gq,
                    float* __restrict__ scales) {
    const int wave = threadIdx.x >> 6;
    const int l    = threadIdx.x & 63;
    const int tile = blockIdx.x * 4 + wave;
    if (tile >= N_NODES / 16) return;
    const int n0   = tile * 16;
    const int lrow = l & 15;
    const int lk   = l >> 4;

    union { short8 v; ushort_t u[8]; } bfrag[4];
    const float* hp = h + (size_t)(n0 + lrow) * D + lk * 8;
#pragma unroll
    for (int kt = 0; kt < 4; ++kt) {
        const float4 q0 = *reinterpret_cast<const float4*>(hp + kt * 32);
        const float4 q1 = *reinterpret_cast<const float4*>(hp + kt * 32 + 4);
        bfrag[kt].u[0] = (ushort_t)f2bf(q0.x);
        bfrag[kt].u[1] = (ushort_t)f2bf(q0.y);
        bfrag[kt].u[2] = (ushort_t)f2bf(q0.z);
        bfrag[kt].u[3] = (ushort_t)f2bf(q0.w);
        bfrag[kt].u[4] = (ushort_t)f2bf(q1.x);
        bfrag[kt].u[5] = (ushort_t)f2bf(q1.y);
        bfrag[kt].u[6] = (ushort_t)f2bf(q1.z);
        bfrag[kt].u[7] = (ushort_t)f2bf(q1.w);
    }

    const uint4* wf = reinterpret_cast<const uint4*>(Wfrag) + l;
    f32x4 acc[8];
#pragma unroll
    for (int jt = 0; jt < 8; ++jt) {
        acc[jt] = (f32x4){0.f, 0.f, 0.f, 0.f};
#pragma unroll
        for (int kt = 0; kt < 4; ++kt) {
            union { uint4 q; short8 v; } af;
            af.q = wf[(jt * 4 + kt) * 64];
            acc[jt] = __builtin_amdgcn_mfma_f32_16x16x32_bf16(
                af.v, bfrag[kt].v, acc[jt], 0, 0, 0);
        }
    }

    float amax = 0.f;
#pragma unroll
    for (int jt = 0; jt < 8; ++jt) {
#pragma unroll
        for (int r = 0; r < 4; ++r) amax = fmaxf(amax, fabsf(acc[jt][r]));
    }
    amax = fmaxf(amax, __shfl_xor(amax, 16));
    amax = fmaxf(amax, __shfl_xor(amax, 32));
    const float s   = amax > 0.f ? amax * (1.f / 127.f) : 1.f;
    const float inv = amax > 0.f ? 127.f / amax : 0.f;

#pragma unroll
    for (int jt = 0; jt < 8; ++jt) {
        const unsigned q0 = (unsigned)((int)rintf(acc[jt][0] * inv) + 128);
        const unsigned q1 = (unsigned)((int)rintf(acc[jt][1] * inv) + 128);
        const unsigned q2 = (unsigned)((int)rintf(acc[jt][2] * inv) + 128);
        const unsigned q3 = (unsigned)((int)rintf(acc[jt][3] * inv) + 128);
        const unsigned pk = q0 | (q1 << 8) | (q2 << 16) | (q3 << 24);
        *reinterpret_cast<unsigned*>(
            Gq + (size_t)(n0 + lrow) * D + jt * 16 + lk * 4) = pk;
    }
    if (l < 16) scales[n0 + l] = s;
}

// ---------------------------------------------------------------------------
// Kernel 3 (prep sweep): per edge e, (a) boundary-detect row_ptr from the
// SORTED edge_rows, (b) vals2[e] = vals[e] * scales[cols[e]].
// ---------------------------------------------------------------------------
__global__ __launch_bounds__(256)
void prep_kernel(const int* __restrict__ rows,
                 const int* __restrict__ cols,
                 const float* __restrict__ vals,
                 const float* __restrict__ scales,
                 int* __restrict__ row_ptr,
                 float* __restrict__ vals2, int n_edges) {
    const int e = blockIdx.x * 256 + threadIdx.x;
    if (e >= n_edges) return;

    vals2[e] = vals[e] * scales[cols[e]];

    const int r0 = rows[e];
    if (e == 0) {
        for (int r = 0; r <= r0; ++r) row_ptr[r] = 0;
    }
    if (e + 1 < n_edges) {
        const int r1 = rows[e + 1];
        for (int r = r0 + 1; r <= r1; ++r) row_ptr[r] = e + 1;
    } else {
        for (int r = r0 + 1; r <= N_NODES; ++r) row_ptr[r] = n_edges;
    }
}

// ---------------------------------------------------------------------------
// Kernel 4: out = relu(S @ dequant(Gq) + b). One node per 16-lane group
// (R6 structure, best measured). Lane il owns feats il*8..il*8+7 (8 int8 =
// uint2 load; group row = 128B = ONE cache line per edge).
// 16-deep main unroll (16 Gq lines in flight per lane), 8-deep secondary,
// scalar tail. PLAIN loads (NT on shared reads measured +50MB fetch, R12).
// ---------------------------------------------------------------------------
__device__ __forceinline__ void accq(float* a, float& vsum, float vs, uint2 g) {
    a[0] += vs * (float)(g.x & 0xffu);
    a[1] += vs * (float)((g.x >> 8) & 0xffu);
    a[2] += vs * (float)((g.x >> 16) & 0xffu);
    a[3] += vs * (float)(g.x >> 24);
    a[4] += vs * (float)(g.y & 0xffu);
    a[5] += vs * (float)((g.y >> 8) & 0xffu);
    a[6] += vs * (float)((g.y >> 16) & 0xffu);
    a[7] += vs * (float)(g.y >> 24);
    vsum += vs;
}

__global__ __launch_bounds__(256)
void gconv_gather_q16_kernel(const int* __restrict__ cols,
                             const float* __restrict__ vals2,
                             const uchar_t* __restrict__ Gq,
                             const float* __restrict__ bias,
                             const int* __restrict__ row_ptr,
                             float* __restrict__ out) {
    const int tid  = blockIdx.x * 256 + threadIdx.x;
    const int node = tid >> 4;
    const int il   = tid & 15;
    const unsigned il8 = (unsigned)il * 8u;

    int e = row_ptr[node];
    const int end = row_ptr[node + 1];

    float a[8];
#pragma unroll
    for (int j = 0; j < 8; ++j) a[j] = 0.f;
    float vsum = 0.f;

    // 16-deep main loop: 16 independent Gq lines in flight per lane
    for (; e + 15 < end; e += 16) {
        int   c[16];
        float v[16];
        uint2 g[16];
#pragma unroll
        for (int i = 0; i < 16; ++i) c[i] = cols[e + i];
#pragma unroll
        for (int i = 0; i < 16; ++i) v[i] = vals2[e + i];
#pragma unroll
        for (int i = 0; i < 16; ++i)
            g[i] = *reinterpret_cast<const uint2*>(Gq + (((unsigned)c[i] << 7) + il8));
#pragma unroll
        for (int i = 0; i < 16; ++i) accq(a, vsum, v[i], g[i]);
    }
    // 8-deep secondary
    for (; e + 7 < end; e += 8) {
        int   c[8];
        float v[8];
        uint2 g[8];
#pragma unroll
        for (int i = 0; i < 8; ++i) c[i] = cols[e + i];
#pragma unroll
        for (int i = 0; i < 8; ++i) v[i] = vals2[e + i];
#pragma unroll
        for (int i = 0; i < 8; ++i)
            g[i] = *reinterpret_cast<const uint2*>(Gq + (((unsigned)c[i] << 7) + il8));
#pragma unroll
        for (int i = 0; i < 8; ++i) accq(a, vsum, v[i], g[i]);
    }
    for (; e < end; ++e) {
        const int   c = cols[e];
        const float v = vals2[e];
        const uint2 g = *reinterpret_cast<const uint2*>(Gq + (((unsigned)c << 7) + il8));
        accq(a, vsum, v, g);
    }

    const float4 b0 = *reinterpret_cast<const float4*>(bias + il8);
    const float4 b1 = *reinterpret_cast<const float4*>(bias + il8 + 4);
    const float corr = 128.f * vsum;
    f32x4 r0, r1;
    r0[0] = a[0] - corr + b0.x; r0[1] = a[1] - corr + b0.y;
    r0[2] = a[2] - corr + b0.z; r0[3] = a[3] - corr + b0.w;
    r1[0] = a[4] - corr + b1.x; r1[1] = a[5] - corr + b1.y;
    r1[2] = a[6] - corr + b1.z; r1[3] = a[7] - corr + b1.w;
#pragma unroll
    for (int i = 0; i < 4; ++i) {
        r0[i] = r0[i] > 0.f ? r0[i] : 0.f;
        r1[i] = r1[i] > 0.f ? r1[i] : 0.f;
    }
    float* op = out + (size_t)node * D + il8;
    *reinterpret_cast<f32x4*>(op)     = r0;
    *reinterpret_cast<f32x4*>(op + 4) = r1;
}

// ---------------------------------------------------------------------------
extern "C" void kernel_launch(void* const* d_in, const int* in_sizes, int n_in,
                              void* d_out, int out_size, void* d_ws,
                              size_t ws_size, hipStream_t stream) {
    const int*   edge_rows = (const int*)d_in[0];
    const int*   edge_cols = (const int*)d_in[1];
    const float* edge_vals = (const float*)d_in[2];
    const float* h         = (const float*)d_in[3];
    const float* W         = (const float*)d_in[4];
    const float* b         = (const float*)d_in[5];
    float*       out       = (float*)d_out;

    const int n_edges = in_sizes[0];

    // ws: [Wfrag 32K|pad64K][row_ptr 400K|pad512K][scales 400K|pad512K]
    //     [Gq 12.8M][vals2 12.8M]   total ~26.8MB
    const size_t OFF_RP = 64 * 1024;
    const size_t OFF_SC = OFF_RP + 512 * 1024;
    const size_t OFF_GQ = OFF_SC + 512 * 1024;
    const size_t OFF_V2 = OFF_GQ + (size_t)N_NODES * D;

    ushort_t* Wfrag   = (ushort_t*)d_ws;
    int*      row_ptr = (int*)((char*)d_ws + OFF_RP);
    float*    scales  = (float*)((char*)d_ws + OFF_SC);
    uchar_t*  Gq      = (uchar_t*)((char*)d_ws + OFF_GQ);
    float*    vals2   = (float*)((char*)d_ws + OFF_V2);

    build_wfrag_kernel<<<32, 64, 0, stream>>>(W, Wfrag);

    const int n_tiles     = N_NODES / 16;  // 6250
    const int gemm_blocks = (n_tiles + 3) / 4;
    gemm_Gq_kernel<<<gemm_blocks, 256, 0, stream>>>(h, Wfrag, Gq, scales);

    prep_kernel<<<(n_edges + 255) / 256, 256, 0, stream>>>(
        edge_rows, edge_cols, edge_vals, scales, row_ptr, vals2, n_edges);

    const int gather_blocks = N_NODES * 16 / 256;  // 6250
    gconv_gather_q16_kernel<<<gather_blocks, 256, 0, stream>>>(
        edge_cols, vals2, Gq, b, row_ptr, out);
}